// Round 14
// baseline (70.053 us; speedup 1.0000x reference)
//
#include <hip/hip_runtime.h>
#include <stdint.h>

#define COLUMNS   1024
#define CELLS     16
#define NUM_CELLS (COLUMNS * CELLS)   // 16384
#define SEGS      32
#define SYNS      128
#define ACT_THR   10
#define NB        2048
#define NWAVES    (NB * 4)            // 256-thread blocks = 4 waves

typedef int            i32x4 __attribute__((ext_vector_type(4)));
typedef float          f32x4 __attribute__((ext_vector_type(4)));

// ---------------------------------------------------------------------------
// K0 (16 blocks x 256): detect prev dtype (int32-bool words are all 0/1;
// random uint8-bool bytes make some int-view word >1 w.h.p.), pack each
// block's 32-word slice of prevbits, and zero the predw bitmask slice.
// ---------------------------------------------------------------------------
__global__ __launch_bounds__(256) void pack_kernel(
    const void* __restrict__ prev, uint32_t* __restrict__ prevbits,
    uint32_t* __restrict__ predw)
{
    __shared__ int s_isu8;
    const int t = threadIdx.x;
    if (t == 0) s_isu8 = 0;
    __syncthreads();
    const int* pi = (const int*)prev;
    int bad = 0;
    for (int k = t; k < NUM_CELLS / 4; k += 256)
        bad |= ((unsigned)pi[k] > 1u) ? 1 : 0;
    unsigned long long bb = __ballot(bad != 0);
    if ((t & 63) == 0 && bb) atomicOr(&s_isu8, 1);
    __syncthreads();

    if (t < 32) {
        const int w = blockIdx.x * 32 + t;
        uint32_t m = 0;
        if (s_isu8) {
            const unsigned char* p = (const unsigned char*)prev + (size_t)w * 32;
            #pragma unroll
            for (int j = 0; j < 32; ++j) m |= (p[j] ? 1u : 0u) << j;
        } else {
            const int* p = pi + (size_t)w * 32;
            #pragma unroll
            for (int j = 0; j < 32; ++j) m |= (p[j] ? 1u : 0u) << j;
        }
        prevbits[w] = m;
        predw[w] = 0;   // predw bitmask zeroed every call (ws not re-poisoned)
    }
}

// ---------------------------------------------------------------------------
// K1 = phase 1+2. Prologue: prevbits (2 KB) + ordered compaction from x.
// Main: per cell, issue ALL 16 conn pair-loads up front (argmax is
// fire-independent -> one memory round per cell, 16 VMEM in flight), then
// the pair-0 vol/cons fire check, then branch-free overlap/argmax from
// registers. Rare !fire path re-derives p-bits from registers and probes
// vol/cons only.
// ---------------------------------------------------------------------------
__global__ __launch_bounds__(256) void p1_kernel(
    const uint32_t* __restrict__ prevbits, const int* __restrict__ x,
    const int* __restrict__ conn, const float* __restrict__ vol,
    const float* __restrict__ cons,
    uint32_t* __restrict__ predw, unsigned char* __restrict__ bestseg)
{
    __shared__ uint32_t sbits[NUM_CELLS / 32];
    __shared__ unsigned short sacols[COLUMNS];
    __shared__ int s_gcnt[16], s_goff[16], s_acount;
    const int t = threadIdx.x, wv = t >> 6, ln = t & 63;

    for (int i = t; i < NUM_CELLS / 32; i += 256) sbits[i] = prevbits[i];

    int ca_[4];
    #pragma unroll
    for (int c2 = 0; c2 < 4; ++c2) {
        const int col = c2 * 256 + t;
        ca_[c2] = (x[col] != 0) ? 1 : 0;
        unsigned long long b = __ballot(ca_[c2] != 0);
        if (ln == 0) s_gcnt[c2 * 4 + wv] = __popcll(b);
    }
    __syncthreads();
    if (t == 0) {
        int s = 0;
        #pragma unroll
        for (int g = 0; g < 16; ++g) { s_goff[g] = s; s += s_gcnt[g]; }
        s_acount = s;
    }
    __syncthreads();
    #pragma unroll
    for (int c2 = 0; c2 < 4; ++c2) {
        unsigned long long b = __ballot(ca_[c2] != 0);
        if (ca_[c2])
            sacols[s_goff[c2 * 4 + wv] + __popcll(b & ((1ULL << ln) - 1ULL))] =
                (unsigned short)(c2 * 256 + t);
    }
    __syncthreads();

    const int nc   = s_acount * CELLS;
    const int half = ln >> 5;
    const int l32  = ln & 31;
    const int gw   = blockIdx.x * 4 + wv;

    for (int idx = gw; idx < nc; idx += NWAVES) {
        const int cell = (int)sacols[idx >> 4] * CELLS + (idx & 15);
        const size_t base = (size_t)cell * (SEGS * SYNS) + (size_t)half * SYNS
                          + l32 * 4;

        // ---- issue ALL 16 conn pair-loads (unconditional, 16 in flight) ----
        i32x4 c[16];
        #pragma unroll
        for (int k = 0; k < 16; ++k)
            c[k] = *(const i32x4*)(conn + base + (size_t)(k * 2) * SYNS);

        // ---- pair-0 vol/cons fire check ----
        int fire;
        {
            f32x4 v = *(const f32x4*)(vol + base);
            f32x4 q = *(const f32x4*)(cons + base);
            int i0 = min(max(c[0].x, 0), NUM_CELLS - 1);
            int i1 = min(max(c[0].y, 0), NUM_CELLS - 1);
            int i2 = min(max(c[0].z, 0), NUM_CELLS - 1);
            int i3 = min(max(c[0].w, 0), NUM_CELLS - 1);
            int p0 = (sbits[i0 >> 5] >> (i0 & 31)) & 1;
            int p1 = (sbits[i1 >> 5] >> (i1 & 31)) & 1;
            int p2 = (sbits[i2 >> 5] >> (i2 & 31)) & 1;
            int p3 = (sbits[i3 >> 5] >> (i3 & 31)) & 1;
            int cn0 = ((v.x > 0.5f) || (q.x > 0.5f)) ? 1 : 0;
            int cn1 = ((v.y > 0.5f) || (q.y > 0.5f)) ? 1 : 0;
            int cn2 = ((v.z > 0.5f) || (q.z > 0.5f)) ? 1 : 0;
            int cn3 = ((v.w > 0.5f) || (q.w > 0.5f)) ? 1 : 0;
            unsigned long long bc0 = __ballot(cn0 && p0);
            unsigned long long bc1 = __ballot(cn1 && p1);
            unsigned long long bc2 = __ballot(cn2 && p2);
            unsigned long long bc3 = __ballot(cn3 && p3);
            int cA = __popcll(bc0 & 0xFFFFFFFFull) + __popcll(bc1 & 0xFFFFFFFFull)
                   + __popcll(bc2 & 0xFFFFFFFFull) + __popcll(bc3 & 0xFFFFFFFFull);
            int cB = __popcll(bc0 >> 32) + __popcll(bc1 >> 32)
                   + __popcll(bc2 >> 32) + __popcll(bc3 >> 32);
            fire = (cA >= ACT_THR) | (cB >= ACT_THR);
        }

        // ---- branch-free overlap/argmax from registers ----
        int bestkey = 0;
        #pragma unroll
        for (int k = 0; k < 16; ++k) {
            const int segA = k * 2;
            int i0 = min(max(c[k].x, 0), NUM_CELLS - 1);
            int i1 = min(max(c[k].y, 0), NUM_CELLS - 1);
            int i2 = min(max(c[k].z, 0), NUM_CELLS - 1);
            int i3 = min(max(c[k].w, 0), NUM_CELLS - 1);
            int p0 = (sbits[i0 >> 5] >> (i0 & 31)) & 1;
            int p1 = (sbits[i1 >> 5] >> (i1 & 31)) & 1;
            int p2 = (sbits[i2 >> 5] >> (i2 & 31)) & 1;
            int p3 = (sbits[i3 >> 5] >> (i3 & 31)) & 1;
            unsigned long long bp0 = __ballot(p0 != 0);
            unsigned long long bp1 = __ballot(p1 != 0);
            unsigned long long bp2 = __ballot(p2 != 0);
            unsigned long long bp3 = __ballot(p3 != 0);
            int oA = __popcll(bp0 & 0xFFFFFFFFull) + __popcll(bp1 & 0xFFFFFFFFull)
                   + __popcll(bp2 & 0xFFFFFFFFull) + __popcll(bp3 & 0xFFFFFFFFull);
            int oB = __popcll(bp0 >> 32) + __popcll(bp1 >> 32)
                   + __popcll(bp2 >> 32) + __popcll(bp3 >> 32);
            bestkey = max(bestkey, (oA << 8) | (255 - segA));   // first-max tiebreak
            bestkey = max(bestkey, (oB << 8) | (254 - segA));
        }

        // ---- rare: fire undecided after pair 0 -> probe vol/cons ----
        if (!fire) {
            for (int k = 1; k < 16 && !fire; ++k) {
                const size_t off = base + (size_t)(k * 2) * SYNS;
                f32x4 v = *(const f32x4*)(vol + off);
                f32x4 q = *(const f32x4*)(cons + off);
                int i0 = min(max(c[k].x, 0), NUM_CELLS - 1);
                int i1 = min(max(c[k].y, 0), NUM_CELLS - 1);
                int i2 = min(max(c[k].z, 0), NUM_CELLS - 1);
                int i3 = min(max(c[k].w, 0), NUM_CELLS - 1);
                int p0 = (sbits[i0 >> 5] >> (i0 & 31)) & 1;
                int p1 = (sbits[i1 >> 5] >> (i1 & 31)) & 1;
                int p2 = (sbits[i2 >> 5] >> (i2 & 31)) & 1;
                int p3 = (sbits[i3 >> 5] >> (i3 & 31)) & 1;
                int cn0 = ((v.x > 0.5f) || (q.x > 0.5f)) ? 1 : 0;
                int cn1 = ((v.y > 0.5f) || (q.y > 0.5f)) ? 1 : 0;
                int cn2 = ((v.z > 0.5f) || (q.z > 0.5f)) ? 1 : 0;
                int cn3 = ((v.w > 0.5f) || (q.w > 0.5f)) ? 1 : 0;
                unsigned long long bc0 = __ballot(cn0 && p0);
                unsigned long long bc1 = __ballot(cn1 && p1);
                unsigned long long bc2 = __ballot(cn2 && p2);
                unsigned long long bc3 = __ballot(cn3 && p3);
                int cA = __popcll(bc0 & 0xFFFFFFFFull) + __popcll(bc1 & 0xFFFFFFFFull)
                       + __popcll(bc2 & 0xFFFFFFFFull) + __popcll(bc3 & 0xFFFFFFFFull);
                int cB = __popcll(bc0 >> 32) + __popcll(bc1 >> 32)
                       + __popcll(bc2 >> 32) + __popcll(bc3 >> 32);
                fire |= (cA >= ACT_THR) | (cB >= ACT_THR);
            }
        }

        if (ln == 0) {
            if (fire) atomicOr(&predw[cell >> 5], 1u << (cell & 31));
            bestseg[cell] = (unsigned char)(255 - (bestkey & 0xFF));
        }
    }
}

// ---------------------------------------------------------------------------
// K2 = mid + phase 3. Prologue: prevbits (2 KB -> learnflag), predw (2 KB)
// -> s_act/newbits, compaction from x; first 64 blocks zero-fill inactive
// outpred; block 0 writes new_active floats + acc. Main: early-exit phase-3
// scan (any-semantics; learning delta inline; clip(x,0,1)>0.5 == x>0.5).
// ---------------------------------------------------------------------------
__global__ __launch_bounds__(256) void p3_kernel(
    const uint32_t* __restrict__ prevbits, const uint32_t* __restrict__ predw,
    const int* __restrict__ x, const float* __restrict__ mod,
    const int* __restrict__ conn, const float* __restrict__ vol,
    const float* __restrict__ cons, const unsigned char* __restrict__ bestseg,
    float* __restrict__ out)
{
    __shared__ uint32_t sprev[NUM_CELLS / 32];
    __shared__ uint32_t snew[NUM_CELLS / 32];
    __shared__ unsigned short sacols[COLUMNS];
    __shared__ unsigned short s_na[COLUMNS];
    __shared__ unsigned char s_act[COLUMNS];
    __shared__ int s_any, s_gcnt[16], s_goff[16], s_acount, s_nact, s_npred;
    const int t = threadIdx.x, wv = t >> 6, ln = t & 63;
    if (t == 0) { s_any = 0; s_nact = 0; s_npred = 0; }
    __syncthreads();

    {
        int any = 0;
        for (int i = t; i < NUM_CELLS / 32; i += 256) {
            uint32_t m = prevbits[i];
            sprev[i] = m;
            any |= (m != 0) ? 1 : 0;
        }
        unsigned long long ba = __ballot(any != 0);
        if (ln == 0 && ba) atomicOr(&s_any, 1);
    }

    int ca_[4];
    #pragma unroll
    for (int c2 = 0; c2 < 4; ++c2) {
        const int col = c2 * 256 + t;
        const int ca = (x[col] != 0) ? 1 : 0;
        ca_[c2] = ca;
        s_act[col] = (unsigned char)ca;
        const uint32_t w = predw[col >> 1];
        const unsigned int pb = (col & 1) ? (w >> 16) : (w & 0xFFFFu);
        const int hp = (pb != 0) ? 1 : 0;
        unsigned int bits = 0;
        if (ca) bits = hp ? pb : 0xFFFFu;   // burst if no prediction
        s_na[col] = (unsigned short)bits;
        unsigned long long b1 = __ballot(ca != 0);
        unsigned long long b2 = __ballot((ca && hp) != 0);
        if (ln == 0) {
            s_gcnt[c2 * 4 + wv] = __popcll(b1);
            if (blockIdx.x == 0) {
                atomicAdd(&s_nact, __popcll(b1));
                atomicAdd(&s_npred, __popcll(b2));
            }
        }
    }
    __syncthreads();
    for (int w = t; w < NUM_CELLS / 32; w += 256)
        snew[w] = (uint32_t)s_na[2 * w] | ((uint32_t)s_na[2 * w + 1] << 16);
    if (t == 0) {
        int s = 0;
        #pragma unroll
        for (int g = 0; g < 16; ++g) { s_goff[g] = s; s += s_gcnt[g]; }
        s_acount = s;
    }
    __syncthreads();
    #pragma unroll
    for (int c2 = 0; c2 < 4; ++c2) {
        unsigned long long b = __ballot(ca_[c2] != 0);
        if (ca_[c2])
            sacols[s_goff[c2 * 4 + wv] + __popcll(b & ((1ULL << ln) - 1ULL))] =
                (unsigned short)(c2 * 256 + t);
    }

    float* outpred = out + NUM_CELLS;
    {   // zero-fill outpred for inactive columns (first 64 blocks, coalesced)
        const int i = blockIdx.x * 256 + t;
        if (i < NUM_CELLS && !s_act[i >> 4]) outpred[i] = 0.0f;
    }
    if (blockIdx.x == 0) {
        for (int g = t; g < NUM_CELLS / 4; g += 256) {
            const uint32_t w = snew[g >> 3];
            const int sh = (g & 7) * 4;
            f32x4 o;
            o.x = (w >> (sh + 0)) & 1 ? 1.0f : 0.0f;
            o.y = (w >> (sh + 1)) & 1 ? 1.0f : 0.0f;
            o.z = (w >> (sh + 2)) & 1 ? 1.0f : 0.0f;
            o.w = (w >> (sh + 3)) & 1 ? 1.0f : 0.0f;
            *(f32x4*)(out + (size_t)g * 4) = o;
        }
    }
    __syncthreads();
    if (blockIdx.x == 0 && t == 0)
        out[2 * NUM_CELLS] = (s_nact > 0)
            ? (float)s_npred / (float)max(s_nact, 1) : 1.0f;

    const int nc   = s_acount * CELLS;
    const int lf   = ((mod[0] != 0.0f) && s_any) ? 1 : 0;
    const float d  = mod[0] * 0.1f;
    const int half = ln >> 5;
    const int l32  = ln & 31;
    const int gw   = blockIdx.x * 4 + wv;

    for (int idx = gw; idx < nc; idx += NWAVES) {
        const int cell = (int)sacols[idx >> 4] * CELLS + (idx & 15);
        const size_t base = (size_t)cell * (SEGS * SYNS);
        const int na  = (snew[cell >> 5] >> (cell & 31)) & 1;
        const int upd = (lf && na) ? (int)bestseg[cell] : -1;
        int fire = 0;
        for (int k = 0; k < 16; ++k) {          // no unroll: early exit
            const int seg = k * 2 + half;
            const size_t off = base + (size_t)seg * SYNS + l32 * 4;
            i32x4 c = *(const i32x4*)(conn + off);
            f32x4 v = *(const f32x4*)(vol + off);
            f32x4 q = *(const f32x4*)(cons + off);
            int i0 = min(max(c.x, 0), NUM_CELLS - 1);
            int i1 = min(max(c.y, 0), NUM_CELLS - 1);
            int i2 = min(max(c.z, 0), NUM_CELLS - 1);
            int i3 = min(max(c.w, 0), NUM_CELLS - 1);
            float vx = v.x, vy = v.y, vz = v.z, vw = v.w;
            if (seg == upd) {
                int pp0 = (sprev[i0 >> 5] >> (i0 & 31)) & 1;
                int pp1 = (sprev[i1 >> 5] >> (i1 & 31)) & 1;
                int pp2 = (sprev[i2 >> 5] >> (i2 & 31)) & 1;
                int pp3 = (sprev[i3 >> 5] >> (i3 & 31)) & 1;
                vx += pp0 ? d : -d; vy += pp1 ? d : -d;
                vz += pp2 ? d : -d; vw += pp3 ? d : -d;
            }
            int cn0 = (vx > 0.5f) || (q.x > 0.5f);
            int cn1 = (vy > 0.5f) || (q.y > 0.5f);
            int cn2 = (vz > 0.5f) || (q.z > 0.5f);
            int cn3 = (vw > 0.5f) || (q.w > 0.5f);
            int pn0 = (snew[i0 >> 5] >> (i0 & 31)) & 1;
            int pn1 = (snew[i1 >> 5] >> (i1 & 31)) & 1;
            int pn2 = (snew[i2 >> 5] >> (i2 & 31)) & 1;
            int pn3 = (snew[i3 >> 5] >> (i3 & 31)) & 1;
            unsigned long long b0 = __ballot(cn0 && pn0);
            unsigned long long b1 = __ballot(cn1 && pn1);
            unsigned long long b2 = __ballot(cn2 && pn2);
            unsigned long long b3 = __ballot(cn3 && pn3);
            int cA = __popcll(b0 & 0xFFFFFFFFull) + __popcll(b1 & 0xFFFFFFFFull)
                   + __popcll(b2 & 0xFFFFFFFFull) + __popcll(b3 & 0xFFFFFFFFull);
            int cB = __popcll(b0 >> 32) + __popcll(b1 >> 32)
                   + __popcll(b2 >> 32) + __popcll(b3 >> 32);
            fire |= (cA >= ACT_THR) | (cB >= ACT_THR);
            if (fire) break;                    // any-semantics: exact early exit
        }
        if (ln == 0) outpred[cell] = fire ? 1.0f : 0.0f;
    }
}

// ---------------------------------------------------------------------------
extern "C" void kernel_launch(void* const* d_in, const int* in_sizes, int n_in,
                              void* d_out, int out_size, void* d_ws, size_t ws_size,
                              hipStream_t stream) {
    const int*   x    = (const int*)d_in[0];
    const float* mod  = (const float*)d_in[1];
    const void*  prev = d_in[2];                 // bool array (dtype auto-detected)
    const int*   conn = (const int*)d_in[3];
    const float* vol  = (const float*)d_in[4];
    const float* cons = (const float*)d_in[5];
    float* out = (float*)d_out;  // [0..N) new_active, [N..2N) new_predictive, [2N] acc

    char* ws = (char*)d_ws;
    uint32_t* prevbits     = (uint32_t*)(ws + 0);           // 2 KiB
    uint32_t* predw        = (uint32_t*)(ws + 4096);        // 2 KiB
    unsigned char* bestseg = (unsigned char*)(ws + 32768);  // 16 KiB

    pack_kernel<<<16, 256, 0, stream>>>(prev, prevbits, predw);
    p1_kernel<<<NB, 256, 0, stream>>>(prevbits, x, conn, vol, cons, predw, bestseg);
    p3_kernel<<<NB, 256, 0, stream>>>(prevbits, predw, x, mod, conn, vol, cons,
                                      bestseg, out);
}

// Round 18
// 45.680 us; speedup vs baseline: 1.5336x; 1.5336x over previous
//
#include <hip/hip_runtime.h>
#include <stdint.h>

#define COLUMNS   1024
#define CELLS     16
#define NUM_CELLS (COLUMNS * CELLS)   // 16384
#define SEGS      32
#define SYNS      128
#define ACT_THR   10
#define NB        2048
#define NWAVES    (NB * 4)            // 256-thread blocks = 4 waves

typedef int            i32x4 __attribute__((ext_vector_type(4)));
typedef float          f32x4 __attribute__((ext_vector_type(4)));

// ---------------------------------------------------------------------------
// K0 (16 blocks x 256): detect prev dtype (int32-bool words are all 0/1;
// random uint8-bool bytes make some int-view word >1 w.h.p.), pack each
// block's 32-word slice of prevbits, and zero the predw bitmask slice.
// ---------------------------------------------------------------------------
__global__ __launch_bounds__(256) void pack_kernel(
    const void* __restrict__ prev, uint32_t* __restrict__ prevbits,
    uint32_t* __restrict__ predw)
{
    __shared__ int s_isu8;
    const int t = threadIdx.x;
    if (t == 0) s_isu8 = 0;
    __syncthreads();
    const int* pi = (const int*)prev;
    int bad = 0;
    for (int k = t; k < NUM_CELLS / 4; k += 256)
        bad |= ((unsigned)pi[k] > 1u) ? 1 : 0;
    unsigned long long bb = __ballot(bad != 0);
    if ((t & 63) == 0 && bb) atomicOr(&s_isu8, 1);
    __syncthreads();

    if (t < 32) {
        const int w = blockIdx.x * 32 + t;
        uint32_t m = 0;
        if (s_isu8) {
            const unsigned char* p = (const unsigned char*)prev + (size_t)w * 32;
            #pragma unroll
            for (int j = 0; j < 32; ++j) m |= (p[j] ? 1u : 0u) << j;
        } else {
            const int* p = pi + (size_t)w * 32;
            #pragma unroll
            for (int j = 0; j < 32; ++j) m |= (p[j] ? 1u : 0u) << j;
        }
        prevbits[w] = m;
        predw[w] = 0;   // predw bitmask zeroed every call (ws not re-poisoned)
    }
}

// ---------------------------------------------------------------------------
// K1 = phase 1+2. Prologue: prevbits (2 KB) + ordered compaction from x.
// Main: per cell, evaluate seg-pair 0 (conn+vol+cons); with dense data the
// fire bit is decided there, and pairs 1..15 run a BRANCH-FREE fully-unrolled
// conn-only argmax loop (compiler batches loads within the register budget —
// NOT a 16-register preload, which crosses the 128-VGPR tier and halves
// occupancy; TLP > single-wave ILP here, round-14 lesson). Rare slow path
// keeps checking vol/cons until fire.
// ---------------------------------------------------------------------------
__global__ __launch_bounds__(256) void p1_kernel(
    const uint32_t* __restrict__ prevbits, const int* __restrict__ x,
    const int* __restrict__ conn, const float* __restrict__ vol,
    const float* __restrict__ cons,
    uint32_t* __restrict__ predw, unsigned char* __restrict__ bestseg)
{
    __shared__ uint32_t sbits[NUM_CELLS / 32];
    __shared__ unsigned short sacols[COLUMNS];
    __shared__ int s_gcnt[16], s_goff[16], s_acount;
    const int t = threadIdx.x, wv = t >> 6, ln = t & 63;

    for (int i = t; i < NUM_CELLS / 32; i += 256) sbits[i] = prevbits[i];

    int ca_[4];
    #pragma unroll
    for (int c2 = 0; c2 < 4; ++c2) {
        const int col = c2 * 256 + t;
        ca_[c2] = (x[col] != 0) ? 1 : 0;
        unsigned long long b = __ballot(ca_[c2] != 0);
        if (ln == 0) s_gcnt[c2 * 4 + wv] = __popcll(b);
    }
    __syncthreads();
    if (t == 0) {
        int s = 0;
        #pragma unroll
        for (int g = 0; g < 16; ++g) { s_goff[g] = s; s += s_gcnt[g]; }
        s_acount = s;
    }
    __syncthreads();
    #pragma unroll
    for (int c2 = 0; c2 < 4; ++c2) {
        unsigned long long b = __ballot(ca_[c2] != 0);
        if (ca_[c2])
            sacols[s_goff[c2 * 4 + wv] + __popcll(b & ((1ULL << ln) - 1ULL))] =
                (unsigned short)(c2 * 256 + t);
    }
    __syncthreads();

    const int nc   = s_acount * CELLS;
    const int half = ln >> 5;
    const int l32  = ln & 31;
    const int gw   = blockIdx.x * 4 + wv;

    for (int idx = gw; idx < nc; idx += NWAVES) {
        const int cell = (int)sacols[idx >> 4] * CELLS + (idx & 15);
        const size_t base = (size_t)cell * (SEGS * SYNS);
        int fire = 0, bestkey = 0;

        // ---- seg-pair 0: conn + vol/cons ----
        {
            const size_t off = base + (size_t)half * SYNS + l32 * 4;
            i32x4 c = *(const i32x4*)(conn + off);
            f32x4 v = *(const f32x4*)(vol + off);
            f32x4 q = *(const f32x4*)(cons + off);
            int i0 = min(max(c.x, 0), NUM_CELLS - 1);
            int i1 = min(max(c.y, 0), NUM_CELLS - 1);
            int i2 = min(max(c.z, 0), NUM_CELLS - 1);
            int i3 = min(max(c.w, 0), NUM_CELLS - 1);
            int p0 = (sbits[i0 >> 5] >> (i0 & 31)) & 1;
            int p1 = (sbits[i1 >> 5] >> (i1 & 31)) & 1;
            int p2 = (sbits[i2 >> 5] >> (i2 & 31)) & 1;
            int p3 = (sbits[i3 >> 5] >> (i3 & 31)) & 1;
            int cn0 = ((v.x > 0.5f) || (q.x > 0.5f)) ? 1 : 0;
            int cn1 = ((v.y > 0.5f) || (q.y > 0.5f)) ? 1 : 0;
            int cn2 = ((v.z > 0.5f) || (q.z > 0.5f)) ? 1 : 0;
            int cn3 = ((v.w > 0.5f) || (q.w > 0.5f)) ? 1 : 0;
            unsigned long long bc0 = __ballot(cn0 && p0);
            unsigned long long bc1 = __ballot(cn1 && p1);
            unsigned long long bc2 = __ballot(cn2 && p2);
            unsigned long long bc3 = __ballot(cn3 && p3);
            unsigned long long bp0 = __ballot(p0 != 0);
            unsigned long long bp1 = __ballot(p1 != 0);
            unsigned long long bp2 = __ballot(p2 != 0);
            unsigned long long bp3 = __ballot(p3 != 0);
            int cA = __popcll(bc0 & 0xFFFFFFFFull) + __popcll(bc1 & 0xFFFFFFFFull)
                   + __popcll(bc2 & 0xFFFFFFFFull) + __popcll(bc3 & 0xFFFFFFFFull);
            int cB = __popcll(bc0 >> 32) + __popcll(bc1 >> 32)
                   + __popcll(bc2 >> 32) + __popcll(bc3 >> 32);
            int oA = __popcll(bp0 & 0xFFFFFFFFull) + __popcll(bp1 & 0xFFFFFFFFull)
                   + __popcll(bp2 & 0xFFFFFFFFull) + __popcll(bp3 & 0xFFFFFFFFull);
            int oB = __popcll(bp0 >> 32) + __popcll(bp1 >> 32)
                   + __popcll(bp2 >> 32) + __popcll(bp3 >> 32);
            fire = (cA >= ACT_THR) | (cB >= ACT_THR);
            bestkey = max((oA << 8) | 255, (oB << 8) | 254);
        }

        if (fire) {
            // ---- fast path: branch-free conn-only argmax, fully unrolled ----
            #pragma unroll
            for (int k = 1; k < 16; ++k) {
                const int segA = k * 2;
                const size_t off = base + (size_t)(segA + half) * SYNS + l32 * 4;
                i32x4 c = *(const i32x4*)(conn + off);
                int i0 = min(max(c.x, 0), NUM_CELLS - 1);
                int i1 = min(max(c.y, 0), NUM_CELLS - 1);
                int i2 = min(max(c.z, 0), NUM_CELLS - 1);
                int i3 = min(max(c.w, 0), NUM_CELLS - 1);
                int p0 = (sbits[i0 >> 5] >> (i0 & 31)) & 1;
                int p1 = (sbits[i1 >> 5] >> (i1 & 31)) & 1;
                int p2 = (sbits[i2 >> 5] >> (i2 & 31)) & 1;
                int p3 = (sbits[i3 >> 5] >> (i3 & 31)) & 1;
                unsigned long long bp0 = __ballot(p0 != 0);
                unsigned long long bp1 = __ballot(p1 != 0);
                unsigned long long bp2 = __ballot(p2 != 0);
                unsigned long long bp3 = __ballot(p3 != 0);
                int oA = __popcll(bp0 & 0xFFFFFFFFull) + __popcll(bp1 & 0xFFFFFFFFull)
                       + __popcll(bp2 & 0xFFFFFFFFull) + __popcll(bp3 & 0xFFFFFFFFull);
                int oB = __popcll(bp0 >> 32) + __popcll(bp1 >> 32)
                       + __popcll(bp2 >> 32) + __popcll(bp3 >> 32);
                bestkey = max(bestkey, (oA << 8) | (255 - segA));
                bestkey = max(bestkey, (oB << 8) | (254 - segA));
            }
        } else {
            // ---- slow path: keep probing vol/cons until fire decided ----
            #pragma unroll 4
            for (int k = 1; k < 16; ++k) {
                const int segA = k * 2;
                const size_t off = base + (size_t)(segA + half) * SYNS + l32 * 4;
                i32x4 c = *(const i32x4*)(conn + off);
                int i0 = min(max(c.x, 0), NUM_CELLS - 1);
                int i1 = min(max(c.y, 0), NUM_CELLS - 1);
                int i2 = min(max(c.z, 0), NUM_CELLS - 1);
                int i3 = min(max(c.w, 0), NUM_CELLS - 1);
                int p0 = (sbits[i0 >> 5] >> (i0 & 31)) & 1;
                int p1 = (sbits[i1 >> 5] >> (i1 & 31)) & 1;
                int p2 = (sbits[i2 >> 5] >> (i2 & 31)) & 1;
                int p3 = (sbits[i3 >> 5] >> (i3 & 31)) & 1;
                unsigned long long bp0 = __ballot(p0 != 0);
                unsigned long long bp1 = __ballot(p1 != 0);
                unsigned long long bp2 = __ballot(p2 != 0);
                unsigned long long bp3 = __ballot(p3 != 0);
                int oA = __popcll(bp0 & 0xFFFFFFFFull) + __popcll(bp1 & 0xFFFFFFFFull)
                       + __popcll(bp2 & 0xFFFFFFFFull) + __popcll(bp3 & 0xFFFFFFFFull);
                int oB = __popcll(bp0 >> 32) + __popcll(bp1 >> 32)
                       + __popcll(bp2 >> 32) + __popcll(bp3 >> 32);
                bestkey = max(bestkey, (oA << 8) | (255 - segA));
                bestkey = max(bestkey, (oB << 8) | (254 - segA));
                if (!fire) {
                    f32x4 v = *(const f32x4*)(vol + off);
                    f32x4 q = *(const f32x4*)(cons + off);
                    int cn0 = ((v.x > 0.5f) || (q.x > 0.5f)) ? 1 : 0;
                    int cn1 = ((v.y > 0.5f) || (q.y > 0.5f)) ? 1 : 0;
                    int cn2 = ((v.z > 0.5f) || (q.z > 0.5f)) ? 1 : 0;
                    int cn3 = ((v.w > 0.5f) || (q.w > 0.5f)) ? 1 : 0;
                    unsigned long long bc0 = __ballot(cn0 && p0);
                    unsigned long long bc1 = __ballot(cn1 && p1);
                    unsigned long long bc2 = __ballot(cn2 && p2);
                    unsigned long long bc3 = __ballot(cn3 && p3);
                    int cA = __popcll(bc0 & 0xFFFFFFFFull) + __popcll(bc1 & 0xFFFFFFFFull)
                           + __popcll(bc2 & 0xFFFFFFFFull) + __popcll(bc3 & 0xFFFFFFFFull);
                    int cB = __popcll(bc0 >> 32) + __popcll(bc1 >> 32)
                           + __popcll(bc2 >> 32) + __popcll(bc3 >> 32);
                    fire |= (cA >= ACT_THR) | (cB >= ACT_THR);
                }
            }
        }

        if (ln == 0) {
            if (fire) atomicOr(&predw[cell >> 5], 1u << (cell & 31));
            bestseg[cell] = (unsigned char)(255 - (bestkey & 0xFF));
        }
    }
}

// ---------------------------------------------------------------------------
// K2 = mid + phase 3. Prologue: prevbits (2 KB -> learnflag), predw (2 KB)
// -> s_act/newbits, compaction from x; first 64 blocks zero-fill inactive
// outpred; block 0 writes new_active floats + acc. Main: early-exit phase-3
// scan (any-semantics; learning delta inline; clip(x,0,1)>0.5 == x>0.5).
// ---------------------------------------------------------------------------
__global__ __launch_bounds__(256) void p3_kernel(
    const uint32_t* __restrict__ prevbits, const uint32_t* __restrict__ predw,
    const int* __restrict__ x, const float* __restrict__ mod,
    const int* __restrict__ conn, const float* __restrict__ vol,
    const float* __restrict__ cons, const unsigned char* __restrict__ bestseg,
    float* __restrict__ out)
{
    __shared__ uint32_t sprev[NUM_CELLS / 32];
    __shared__ uint32_t snew[NUM_CELLS / 32];
    __shared__ unsigned short sacols[COLUMNS];
    __shared__ unsigned short s_na[COLUMNS];
    __shared__ unsigned char s_act[COLUMNS];
    __shared__ int s_any, s_gcnt[16], s_goff[16], s_acount, s_nact, s_npred;
    const int t = threadIdx.x, wv = t >> 6, ln = t & 63;
    if (t == 0) { s_any = 0; s_nact = 0; s_npred = 0; }
    __syncthreads();

    {
        int any = 0;
        for (int i = t; i < NUM_CELLS / 32; i += 256) {
            uint32_t m = prevbits[i];
            sprev[i] = m;
            any |= (m != 0) ? 1 : 0;
        }
        unsigned long long ba = __ballot(any != 0);
        if (ln == 0 && ba) atomicOr(&s_any, 1);
    }

    int ca_[4];
    #pragma unroll
    for (int c2 = 0; c2 < 4; ++c2) {
        const int col = c2 * 256 + t;
        const int ca = (x[col] != 0) ? 1 : 0;
        ca_[c2] = ca;
        s_act[col] = (unsigned char)ca;
        const uint32_t w = predw[col >> 1];
        const unsigned int pb = (col & 1) ? (w >> 16) : (w & 0xFFFFu);
        const int hp = (pb != 0) ? 1 : 0;
        unsigned int bits = 0;
        if (ca) bits = hp ? pb : 0xFFFFu;   // burst if no prediction
        s_na[col] = (unsigned short)bits;
        unsigned long long b1 = __ballot(ca != 0);
        unsigned long long b2 = __ballot((ca && hp) != 0);
        if (ln == 0) {
            s_gcnt[c2 * 4 + wv] = __popcll(b1);
            if (blockIdx.x == 0) {
                atomicAdd(&s_nact, __popcll(b1));
                atomicAdd(&s_npred, __popcll(b2));
            }
        }
    }
    __syncthreads();
    for (int w = t; w < NUM_CELLS / 32; w += 256)
        snew[w] = (uint32_t)s_na[2 * w] | ((uint32_t)s_na[2 * w + 1] << 16);
    if (t == 0) {
        int s = 0;
        #pragma unroll
        for (int g = 0; g < 16; ++g) { s_goff[g] = s; s += s_gcnt[g]; }
        s_acount = s;
    }
    __syncthreads();
    #pragma unroll
    for (int c2 = 0; c2 < 4; ++c2) {
        unsigned long long b = __ballot(ca_[c2] != 0);
        if (ca_[c2])
            sacols[s_goff[c2 * 4 + wv] + __popcll(b & ((1ULL << ln) - 1ULL))] =
                (unsigned short)(c2 * 256 + t);
    }

    float* outpred = out + NUM_CELLS;
    {   // zero-fill outpred for inactive columns (first 64 blocks, coalesced)
        const int i = blockIdx.x * 256 + t;
        if (i < NUM_CELLS && !s_act[i >> 4]) outpred[i] = 0.0f;
    }
    if (blockIdx.x == 0) {
        for (int g = t; g < NUM_CELLS / 4; g += 256) {
            const uint32_t w = snew[g >> 3];
            const int sh = (g & 7) * 4;
            f32x4 o;
            o.x = (w >> (sh + 0)) & 1 ? 1.0f : 0.0f;
            o.y = (w >> (sh + 1)) & 1 ? 1.0f : 0.0f;
            o.z = (w >> (sh + 2)) & 1 ? 1.0f : 0.0f;
            o.w = (w >> (sh + 3)) & 1 ? 1.0f : 0.0f;
            *(f32x4*)(out + (size_t)g * 4) = o;
        }
    }
    __syncthreads();
    if (blockIdx.x == 0 && t == 0)
        out[2 * NUM_CELLS] = (s_nact > 0)
            ? (float)s_npred / (float)max(s_nact, 1) : 1.0f;

    const int nc   = s_acount * CELLS;
    const int lf   = ((mod[0] != 0.0f) && s_any) ? 1 : 0;
    const float d  = mod[0] * 0.1f;
    const int half = ln >> 5;
    const int l32  = ln & 31;
    const int gw   = blockIdx.x * 4 + wv;

    for (int idx = gw; idx < nc; idx += NWAVES) {
        const int cell = (int)sacols[idx >> 4] * CELLS + (idx & 15);
        const size_t base = (size_t)cell * (SEGS * SYNS);
        const int na  = (snew[cell >> 5] >> (cell & 31)) & 1;
        const int upd = (lf && na) ? (int)bestseg[cell] : -1;
        int fire = 0;
        for (int k = 0; k < 16; ++k) {          // no unroll: early exit
            const int seg = k * 2 + half;
            const size_t off = base + (size_t)seg * SYNS + l32 * 4;
            i32x4 c = *(const i32x4*)(conn + off);
            f32x4 v = *(const f32x4*)(vol + off);
            f32x4 q = *(const f32x4*)(cons + off);
            int i0 = min(max(c.x, 0), NUM_CELLS - 1);
            int i1 = min(max(c.y, 0), NUM_CELLS - 1);
            int i2 = min(max(c.z, 0), NUM_CELLS - 1);
            int i3 = min(max(c.w, 0), NUM_CELLS - 1);
            float vx = v.x, vy = v.y, vz = v.z, vw = v.w;
            if (seg == upd) {
                int pp0 = (sprev[i0 >> 5] >> (i0 & 31)) & 1;
                int pp1 = (sprev[i1 >> 5] >> (i1 & 31)) & 1;
                int pp2 = (sprev[i2 >> 5] >> (i2 & 31)) & 1;
                int pp3 = (sprev[i3 >> 5] >> (i3 & 31)) & 1;
                vx += pp0 ? d : -d; vy += pp1 ? d : -d;
                vz += pp2 ? d : -d; vw += pp3 ? d : -d;
            }
            int cn0 = (vx > 0.5f) || (q.x > 0.5f);
            int cn1 = (vy > 0.5f) || (q.y > 0.5f);
            int cn2 = (vz > 0.5f) || (q.z > 0.5f);
            int cn3 = (vw > 0.5f) || (q.w > 0.5f);
            int pn0 = (snew[i0 >> 5] >> (i0 & 31)) & 1;
            int pn1 = (snew[i1 >> 5] >> (i1 & 31)) & 1;
            int pn2 = (snew[i2 >> 5] >> (i2 & 31)) & 1;
            int pn3 = (snew[i3 >> 5] >> (i3 & 31)) & 1;
            unsigned long long b0 = __ballot(cn0 && pn0);
            unsigned long long b1 = __ballot(cn1 && pn1);
            unsigned long long b2 = __ballot(cn2 && pn2);
            unsigned long long b3 = __ballot(cn3 && pn3);
            int cA = __popcll(b0 & 0xFFFFFFFFull) + __popcll(b1 & 0xFFFFFFFFull)
                   + __popcll(b2 & 0xFFFFFFFFull) + __popcll(b3 & 0xFFFFFFFFull);
            int cB = __popcll(b0 >> 32) + __popcll(b1 >> 32)
                   + __popcll(b2 >> 32) + __popcll(b3 >> 32);
            fire |= (cA >= ACT_THR) | (cB >= ACT_THR);
            if (fire) break;                    // any-semantics: exact early exit
        }
        if (ln == 0) outpred[cell] = fire ? 1.0f : 0.0f;
    }
}

// ---------------------------------------------------------------------------
extern "C" void kernel_launch(void* const* d_in, const int* in_sizes, int n_in,
                              void* d_out, int out_size, void* d_ws, size_t ws_size,
                              hipStream_t stream) {
    const int*   x    = (const int*)d_in[0];
    const float* mod  = (const float*)d_in[1];
    const void*  prev = d_in[2];                 // bool array (dtype auto-detected)
    const int*   conn = (const int*)d_in[3];
    const float* vol  = (const float*)d_in[4];
    const float* cons = (const float*)d_in[5];
    float* out = (float*)d_out;  // [0..N) new_active, [N..2N) new_predictive, [2N] acc

    char* ws = (char*)d_ws;
    uint32_t* prevbits     = (uint32_t*)(ws + 0);           // 2 KiB
    uint32_t* predw        = (uint32_t*)(ws + 4096);        // 2 KiB
    unsigned char* bestseg = (unsigned char*)(ws + 32768);  // 16 KiB

    pack_kernel<<<16, 256, 0, stream>>>(prev, prevbits, predw);
    p1_kernel<<<NB, 256, 0, stream>>>(prevbits, x, conn, vol, cons, predw, bestseg);
    p3_kernel<<<NB, 256, 0, stream>>>(prevbits, predw, x, mod, conn, vol, cons,
                                      bestseg, out);
}